// Round 1
// baseline (3455.662 us; speedup 1.0000x reference)
//
#include <hip/hip_runtime.h>
#include <math.h>

#define IC   2401
#define BSZ  256
#define D    8
#define OC   8
#define CS   16
#define OCC  128   // OC*CS

__device__ __forceinline__ float dot8(const float4 w0, const float4 w1,
                                      const float4 x0, const float4 x1) {
    float t = w0.x * x0.x;
    t = fmaf(w0.y, x0.y, t);
    t = fmaf(w0.z, x0.z, t);
    t = fmaf(w0.w, x0.w, t);
    t = fmaf(w1.x, x1.x, t);
    t = fmaf(w1.y, x1.y, t);
    t = fmaf(w1.z, x1.z, t);
    t = fmaf(w1.w, x1.w, t);
    return t;
}

// s_part[iy][b][oc] = sum_{i in chunk iy} c[i,o] * (W[i,oc,:] . x[b,i,:])
// grid = (16 b-groups, ni chunks), block = 256 threads.
// Thread tile: 2 b x 4 oc (oc within one o, so c is scalar per thread).
template<bool FIRST>
__global__ __launch_bounds__(256)
void s_kernel(const float* __restrict__ x, const float* __restrict__ W,
              const float* __restrict__ cij, float* __restrict__ spart,
              int chunk)
{
    const int bg  = blockIdx.x;        // 0..15
    const int iy  = blockIdx.y;        // 0..ni-1
    const int tid = threadIdx.x;
    const int g   = tid & 31;          // oc group: oc = 4*g..4*g+3
    const int bh  = tid >> 5;          // 0..7
    const int b0  = bg * 16 + bh * 2;
    const int oc0 = g * 4;
    const int o   = g >> 2;            // fixed output-capsule per thread

    int i0 = iy * chunk;
    int i1 = i0 + chunk; if (i1 > IC) i1 = IC;

    const float4* __restrict__ W4 = (const float4*)W;
    const float4* __restrict__ x4 = (const float4*)x;

    float acc[2][4];
#pragma unroll
    for (int j = 0; j < 2; ++j)
#pragma unroll
        for (int k = 0; k < 4; ++k) acc[j][k] = 0.0f;

    for (int i = i0; i < i1; ++i) {
        const float c = FIRST ? 0.125f : cij[i * OC + o];
        const float4* xp0 = x4 + ((size_t)b0 * IC + i) * 2;
        const float4* xp1 = x4 + ((size_t)(b0 + 1) * IC + i) * 2;
        const float4 xa0 = xp0[0], xa1 = xp0[1];
        const float4 xb0 = xp1[0], xb1 = xp1[1];
        const float4* wp = W4 + ((size_t)i * OCC + oc0) * 2;
#pragma unroll
        for (int k = 0; k < 4; ++k) {
            const float4 w0 = wp[2 * k];
            const float4 w1 = wp[2 * k + 1];
            const float t0 = dot8(w0, w1, xa0, xa1);
            const float t1 = dot8(w0, w1, xb0, xb1);
            acc[0][k] = fmaf(c, t0, acc[0][k]);
            acc[1][k] = fmaf(c, t1, acc[1][k]);
        }
    }

    float* op = spart + ((size_t)iy * BSZ + b0) * OCC + oc0;
    *(float4*)op         = make_float4(acc[0][0], acc[0][1], acc[0][2], acc[0][3]);
    *(float4*)(op + OCC) = make_float4(acc[1][0], acc[1][1], acc[1][2], acc[1][3]);
}

// Reduce ni split-K partials, then squash per (b,o) row of 16.
__global__ __launch_bounds__(256)
void squash_kernel(const float* __restrict__ spart, float* __restrict__ vout, int ni)
{
    const int row = blockIdx.x * blockDim.x + threadIdx.x;   // 0..2047
    if (row >= BSZ * OC) return;

    float s[CS];
#pragma unroll
    for (int j = 0; j < CS; ++j) s[j] = 0.0f;

    for (int k = 0; k < ni; ++k) {
        const float4* p = (const float4*)(spart + (size_t)k * BSZ * OCC + (size_t)row * CS);
#pragma unroll
        for (int q = 0; q < 4; ++q) {
            const float4 t = p[q];
            s[4 * q + 0] += t.x; s[4 * q + 1] += t.y;
            s[4 * q + 2] += t.z; s[4 * q + 3] += t.w;
        }
    }

    float ms = 0.0f;
#pragma unroll
    for (int j = 0; j < CS; ++j) ms = fmaf(s[j], s[j], ms);
    const float scale = sqrtf(ms) / (1.0f + ms);   // mag/(1+mag^2) == mag_sq/(1+mag_sq)/mag

    float4* o4 = (float4*)(vout + (size_t)row * CS);
#pragma unroll
    for (int q = 0; q < 4; ++q)
        o4[q] = make_float4(s[4 * q + 0] * scale, s[4 * q + 1] * scale,
                            s[4 * q + 2] * scale, s[4 * q + 3] * scale);
}

// Per block: 4 values of i. a[i,o] = (1/B) sum_{b,c} (W[i,o,c,:].x[b,i,:]) v[b,o,c];
// b_ij += a; c_ij = softmax_o(b_ij). thread = b; W staged in LDS (broadcast reads).
template<bool FIRST>
__global__ __launch_bounds__(256)
void a_kernel(const float* __restrict__ x, const float* __restrict__ W,
              const float* __restrict__ v, float* __restrict__ bij,
              float* __restrict__ cij)
{
    __shared__ __align__(16) float Wl[4 * OCC * D];   // 16 KB
    __shared__ float red[4 * 32];                      // 4 waves x (4 i x 8 o)

    const int tid  = threadIdx.x;          // = b
    const int i0   = blockIdx.x * 4;
    const int icnt = (IC - i0 < 4) ? (IC - i0) : 4;

    // stage W[i0..i0+3] (clamped tail reads stay in-bounds; garbage rows unused)
    {
        const float4* Wg = (const float4*)W;
        float4* Wl4 = (float4*)Wl;
        const size_t gmax = (size_t)IC * (OCC * D / 4) - 1;
#pragma unroll
        for (int q = 0; q < 4; ++q) {
            size_t gidx = (size_t)i0 * (OCC * D / 4) + (size_t)q * 256 + tid;
            if (gidx > gmax) gidx = gmax;
            Wl4[q * 256 + tid] = Wg[gidx];
        }
    }
    __syncthreads();

    // x[b, i0+k, :] in registers (clamped for tail)
    const float4* x4 = (const float4*)x;
    float4 xr[4][2];
#pragma unroll
    for (int k = 0; k < 4; ++k) {
        int ii = i0 + k; if (ii >= IC) ii = IC - 1;
        const float4* xp = x4 + ((size_t)tid * IC + ii) * 2;
        xr[k][0] = xp[0]; xr[k][1] = xp[1];
    }

    float a[4][8];
#pragma unroll
    for (int k = 0; k < 4; ++k)
#pragma unroll
        for (int o = 0; o < 8; ++o) a[k][o] = 0.0f;

    const float4* v4 = (const float4*)(v + (size_t)tid * OCC);
#pragma unroll
    for (int o = 0; o < 8; ++o) {
        const float4 v0 = v4[o * 4 + 0], v1 = v4[o * 4 + 1];
        const float4 v2 = v4[o * 4 + 2], v3 = v4[o * 4 + 3];
        const float vv[16] = { v0.x, v0.y, v0.z, v0.w, v1.x, v1.y, v1.z, v1.w,
                               v2.x, v2.y, v2.z, v2.w, v3.x, v3.y, v3.z, v3.w };
#pragma unroll
        for (int k = 0; k < 4; ++k) {
#pragma unroll
            for (int c = 0; c < CS; ++c) {
                const float4* wp = (const float4*)(Wl + ((size_t)k * OCC + o * CS + c) * D);
                const float t = dot8(wp[0], wp[1], xr[k][0], xr[k][1]);
                a[k][o] = fmaf(t, vv[c], a[k][o]);
            }
        }
    }

    // reduce each a[k][o] over 256 threads: 64-lane shuffle tree + LDS across 4 waves
#pragma unroll
    for (int k = 0; k < 4; ++k)
#pragma unroll
        for (int o = 0; o < 8; ++o) {
            float s = a[k][o];
            s += __shfl_xor(s, 32); s += __shfl_xor(s, 16); s += __shfl_xor(s, 8);
            s += __shfl_xor(s, 4);  s += __shfl_xor(s, 2);  s += __shfl_xor(s, 1);
            if ((tid & 63) == 0) red[(tid >> 6) * 32 + k * 8 + o] = s;
        }
    __syncthreads();

    if (tid < 32) {
        const int k = tid >> 3, o = tid & 7;
        if (k < icnt) {
            const int i = i0 + k;
            const float s = red[0 * 32 + k * 8 + o] + red[1 * 32 + k * 8 + o]
                          + red[2 * 32 + k * 8 + o] + red[3 * 32 + k * 8 + o];
            const float anew = s * (1.0f / 256.0f);
            const float bv = FIRST ? anew : (bij[i * OC + o] + anew);
            bij[i * OC + o] = bv;
            // softmax over o within this aligned 8-lane group
            float mx = bv;
            mx = fmaxf(mx, __shfl_xor(mx, 4));
            mx = fmaxf(mx, __shfl_xor(mx, 2));
            mx = fmaxf(mx, __shfl_xor(mx, 1));
            const float e = expf(bv - mx);
            float sum = e;
            sum += __shfl_xor(sum, 4); sum += __shfl_xor(sum, 2); sum += __shfl_xor(sum, 1);
            cij[i * OC + o] = e / sum;
        }
    }
}

extern "C" void kernel_launch(void* const* d_in, const int* in_sizes, int n_in,
                              void* d_out, int out_size, void* d_ws, size_t ws_size,
                              hipStream_t stream)
{
    const float* x = (const float*)d_in[0];   // [256, 2401, 8]
    const float* W = (const float*)d_in[1];   // [2401, 8, 16, 8]
    float* out = (float*)d_out;               // [256, 8, 16]

    // split-K factor for s_kernel; shrink if workspace is small
    int ni = 16;
    while (ni > 1 &&
           (size_t)ni * BSZ * OCC * 4 + (size_t)BSZ * OCC * 4 + (size_t)IC * OC * 8 > ws_size)
        ni >>= 1;
    const int chunk = (IC + ni - 1) / ni;

    float* spart = (float*)d_ws;                       // [ni][256][128]
    float* v     = spart + (size_t)ni * BSZ * OCC;     // [256][128]
    float* bij   = v + (size_t)BSZ * OCC;              // [2401][8]
    float* cij   = bij + (size_t)IC * OC;              // [2401][8]

    const dim3 sgrid(16, ni);
    const int ablocks = (IC + 3) / 4;   // 601

    // iter 0 (c uniform = 1/8)
    s_kernel<true><<<sgrid, 256, 0, stream>>>(x, W, nullptr, spart, chunk);
    squash_kernel<<<8, 256, 0, stream>>>(spart, v, ni);
    a_kernel<true><<<ablocks, 256, 0, stream>>>(x, W, v, bij, cij);
    // iter 1
    s_kernel<false><<<sgrid, 256, 0, stream>>>(x, W, cij, spart, chunk);
    squash_kernel<<<8, 256, 0, stream>>>(spart, v, ni);
    a_kernel<false><<<ablocks, 256, 0, stream>>>(x, W, v, bij, cij);
    // iter 2 (final)
    s_kernel<false><<<sgrid, 256, 0, stream>>>(x, W, cij, spart, chunk);
    squash_kernel<<<8, 256, 0, stream>>>(spart, out, ni);
}

// Round 2
// 380.870 us; speedup vs baseline: 9.0731x; 9.0731x over previous
//
#include <hip/hip_runtime.h>
#include <math.h>

#define IC   2401
#define BSZ  256
#define D    8
#define OC   8
#define CS   16
#define OCC  128   // OC*CS

__device__ __forceinline__ float fma8(float a, const float4 w0, const float4 w1,
                                      const float4 x0, const float4 x1) {
    a = fmaf(w0.x, x0.x, a); a = fmaf(w0.y, x0.y, a);
    a = fmaf(w0.z, x0.z, a); a = fmaf(w0.w, x0.w, a);
    a = fmaf(w1.x, x1.x, a); a = fmaf(w1.y, x1.y, a);
    a = fmaf(w1.z, x1.z, a); a = fmaf(w1.w, x1.w, a);
    return a;
}

// -------- s partials: spart[iy][b][oc] = sum_{i in chunk} c[i,o]*(W[i,oc,:].x[b,i,:])
// grid (4 b-groups, ni chunks), 128 threads. Block: 64b x 128oc; thread 8b x 8oc.
// c is folded into W at staging time (also zeroes tail i's).
template<bool FIRST>
__global__ __launch_bounds__(128, 2)
void s_kernel(const float* __restrict__ x, const float* __restrict__ W,
              const float* __restrict__ cij, float* __restrict__ spart, int chunk)
{
    __shared__ float xs[64 * 68];     // x[b][i*8+d], pad 68 (2-way max)
    __shared__ float wsm[8 * 1088];   // (c*W)[i][ cg*68 + u*8 + d ] swizzle: oc*8+(oc>>3)*4

    const int tid = threadIdx.x;
    const int bg  = blockIdx.x;
    const int iy  = blockIdx.y;
    const int bh  = tid >> 4;         // 0..7 ; thread b's = bh + s*8
    const int cg  = tid & 15;         // oc0 = cg*8
    const int bb0 = bg * 64;

    int i0 = iy * chunk;
    int i1 = i0 + chunk; if (i1 > IC) i1 = IC;

    float acc[8][8];
#pragma unroll
    for (int s = 0; s < 8; ++s)
#pragma unroll
        for (int u = 0; u < 8; ++u) acc[s][u] = 0.0f;

    const float4* x4 = (const float4*)x;
    const float4* W4 = (const float4*)W;

    for (int ib = i0; ib < i1; ib += 8) {
        __syncthreads();
        // stage x[bb0..bb0+63][ib..ib+7][*]  (clamped reads; tails neutralized via c=0)
        {
            const int b = tid >> 1, j = tid & 1;
            const size_t xbase = (size_t)(bb0 + b) * IC;
#pragma unroll
            for (int k = 0; k < 8; ++k) {
                const int f  = j * 8 + k;        // float4 slot 0..15
                const int il = f >> 1, h = f & 1;
                const int gi = min(ib + il, IC - 1);
                *(float4*)&xs[b * 68 + il * 8 + h * 4] = x4[(xbase + gi) * 2 + h];
            }
        }
        // stage c*W
        {
#pragma unroll
            for (int k = 0; k < 16; ++k) {
                const int flat = tid * 16 + k;   // 0..2047 float4s of batch
                const int gi = flat >> 8;        // i-local 0..7
                const int oc = (flat >> 1) & 127;
                const int h  = flat & 1;
                const int ii = ib + gi;
                float c = 0.0f;
                if (ii < i1) c = FIRST ? 0.125f : cij[ii * OC + (oc >> 4)];
                const int ic = min(ii, IC - 1);
                float4 w = W4[((size_t)ic * 128 + oc) * 2 + h];
                w.x *= c; w.y *= c; w.z *= c; w.w *= c;
                *(float4*)&wsm[gi * 1088 + oc * 8 + (oc >> 3) * 4 + h * 4] = w;
            }
        }
        __syncthreads();
#pragma unroll
        for (int il = 0; il < 8; ++il) {
            float4 xv[8][2];
#pragma unroll
            for (int s = 0; s < 8; ++s) {
                xv[s][0] = *(const float4*)&xs[(bh + s * 8) * 68 + il * 8];
                xv[s][1] = *(const float4*)&xs[(bh + s * 8) * 68 + il * 8 + 4];
            }
            const float* wr = &wsm[il * 1088 + cg * 68];  // oc=cg*8+u -> cg*68+u*8
#pragma unroll
            for (int u = 0; u < 8; ++u) {
                const float4 w0 = *(const float4*)&wr[u * 8];
                const float4 w1 = *(const float4*)&wr[u * 8 + 4];
#pragma unroll
                for (int s = 0; s < 8; ++s)
                    acc[s][u] = fma8(acc[s][u], w0, w1, xv[s][0], xv[s][1]);
            }
        }
    }

    const int oc0 = cg * 8;
    float* op = spart + ((size_t)iy * BSZ + bb0) * OCC;
#pragma unroll
    for (int s = 0; s < 8; ++s) {
        float* r = op + (size_t)(bh + s * 8) * OCC + oc0;
        *(float4*)r       = make_float4(acc[s][0], acc[s][1], acc[s][2], acc[s][3]);
        *(float4*)(r + 4) = make_float4(acc[s][4], acc[s][5], acc[s][6], acc[s][7]);
    }
}

// -------- reduce ni split-K partials + squash. 32 blocks x 256 thr; 64 rows/block,
// 4 k-quarters per row (one per wave), LDS reduce.
__global__ __launch_bounds__(256)
void squash_kernel(const float* __restrict__ spart, float* __restrict__ vout, int ni)
{
    __shared__ float red[256 * 17];
    const int tid = threadIdx.x;
    const int r   = tid & 63;
    const int kq  = tid >> 6;
    const int row = blockIdx.x * 64 + r;   // (b,o) row 0..2047

    float s[CS];
#pragma unroll
    for (int j = 0; j < CS; ++j) s[j] = 0.0f;

    for (int k = kq; k < ni; k += 4) {
        const float4* p = (const float4*)(spart + (size_t)k * BSZ * OCC + (size_t)row * CS);
#pragma unroll
        for (int q = 0; q < 4; ++q) {
            const float4 t = p[q];
            s[4 * q + 0] += t.x; s[4 * q + 1] += t.y;
            s[4 * q + 2] += t.z; s[4 * q + 3] += t.w;
        }
    }
#pragma unroll
    for (int j = 0; j < CS; ++j) red[tid * 17 + j] = s[j];
    __syncthreads();
    if (tid < 64) {
#pragma unroll
        for (int j = 0; j < CS; ++j)
            s[j] = red[r * 17 + j] + red[(64 + r) * 17 + j]
                 + red[(128 + r) * 17 + j] + red[(192 + r) * 17 + j];
        float ms = 0.0f;
#pragma unroll
        for (int j = 0; j < CS; ++j) ms = fmaf(s[j], s[j], ms);
        const float scale = sqrtf(ms) / (1.0f + ms);   // == mag_sq/(1+mag_sq)/mag
        float4* o4 = (float4*)(vout + (size_t)row * CS);
#pragma unroll
        for (int q = 0; q < 4; ++q)
            o4[q] = make_float4(s[4 * q + 0] * scale, s[4 * q + 1] * scale,
                                s[4 * q + 2] * scale, s[4 * q + 3] * scale);
    }
}

// -------- agreement: block = 8 i's. Phase 1: H[(i,d)][oc] = sum_b x[b,i,d]*v[b,oc]
// (64x128x256 GEMM, x/v in LDS, 8x8 reg tile). Phase 2: a[i,o] = sum_{c,d} W*H,
// fused b_ij update + softmax. No spills, no cross-block reduction.
template<bool FIRST>
__global__ __launch_bounds__(128, 2)
void a_kernel(const float* __restrict__ x, const float* __restrict__ W,
              const float* __restrict__ v, float* __restrict__ bij,
              float* __restrict__ cij)
{
    __shared__ float sm[4352 + 8960];   // 53.25 KB
    float* xls = sm;                    // [64 b][68]  rows i*8+d
    float* vls = sm + 4352;             // [64 b][140] swizzle oc + (oc>>5)*4

    const int tid = threadIdx.x;        // 0..127
    const int i0  = blockIdx.x * 8;
    const int rg  = tid >> 4;           // 0..7 -> rows r0..r0+7 (one i)
    const int cg  = tid & 15;           // cols c0..c0+7
    const int r0  = rg * 8;
    const int c0  = cg * 8;
    const int cp  = c0 + ((c0 >> 5) << 2);

    float acc[8][8];
#pragma unroll
    for (int a = 0; a < 8; ++a)
#pragma unroll
        for (int b = 0; b < 8; ++b) acc[a][b] = 0.0f;

    const float4* x4 = (const float4*)x;
    const float4* v4 = (const float4*)v;

    for (int bc = 0; bc < 4; ++bc) {    // batch chunks of 64
        const int b0 = bc * 64;
        __syncthreads();
        {
            const int b = tid >> 1, j = tid & 1;
            const size_t xb = (size_t)(b0 + b) * IC;
#pragma unroll
            for (int k = 0; k < 8; ++k) {
                const int f  = j * 8 + k;
                const int il = f >> 1, h = f & 1;
                const int gi = min(i0 + il, IC - 1);
                *(float4*)&xls[b * 68 + il * 8 + h * 4] = x4[(xb + gi) * 2 + h];
            }
            const size_t vb = (size_t)(b0 + b) * 32;
#pragma unroll
            for (int k = 0; k < 16; ++k) {
                const int q  = j * 16 + k;      // float4 slot 0..31
                const int oc = q * 4;
                *(float4*)&vls[b * 140 + oc + ((oc >> 5) << 2)] = v4[vb + q];
            }
        }
        __syncthreads();
#pragma unroll 2
        for (int bb = 0; bb < 64; ++bb) {
            const float4 x0 = *(const float4*)&xls[bb * 68 + r0];
            const float4 x1 = *(const float4*)&xls[bb * 68 + r0 + 4];
            const float4 va = *(const float4*)&vls[bb * 140 + cp];
            const float4 vb2 = *(const float4*)&vls[bb * 140 + cp + 4];
            const float xr[8] = {x0.x, x0.y, x0.z, x0.w, x1.x, x1.y, x1.z, x1.w};
            const float vr[8] = {va.x, va.y, va.z, va.w, vb2.x, vb2.y, vb2.z, vb2.w};
#pragma unroll
            for (int rr = 0; rr < 8; ++rr)
#pragma unroll
                for (int cc = 0; cc < 8; ++cc)
                    acc[rr][cc] = fmaf(xr[rr], vr[cc], acc[rr][cc]);
        }
    }

    __syncthreads();
    float* H = sm;                      // [64 rows][132]
#pragma unroll
    for (int rr = 0; rr < 8; ++rr) {
        *(float4*)&H[(r0 + rr) * 132 + c0]     = make_float4(acc[rr][0], acc[rr][1], acc[rr][2], acc[rr][3]);
        *(float4*)&H[(r0 + rr) * 132 + c0 + 4] = make_float4(acc[rr][4], acc[rr][5], acc[rr][6], acc[rr][7]);
    }
    __syncthreads();

    // phase 2: tid = il*16 + oo*2 + ch ; each (il,oo) split over 2 c-halves
    const int il = tid >> 4;
    const int oo = (tid >> 1) & 7;
    const int ch = tid & 1;
    const int gi = min(i0 + il, IC - 1);
    const float4* Wg = (const float4*)W + ((size_t)gi * 128 + oo * 16 + ch * 8) * 2;

    float wv[8][8];
#pragma unroll
    for (int cc = 0; cc < 8; ++cc) {
        const float4 a0 = Wg[cc * 2], a1 = Wg[cc * 2 + 1];
        wv[cc][0] = a0.x; wv[cc][1] = a0.y; wv[cc][2] = a0.z; wv[cc][3] = a0.w;
        wv[cc][4] = a1.x; wv[cc][5] = a1.y; wv[cc][6] = a1.z; wv[cc][7] = a1.w;
    }
    float p = 0.0f;
#pragma unroll
    for (int d = 0; d < 8; ++d) {
        const float* hr = &H[(il * 8 + d) * 132 + oo * 16 + ch * 8];
        const float4 h0 = *(const float4*)hr;
        const float4 h1 = *(const float4*)(hr + 4);
        p = fmaf(h0.x, wv[0][d], p); p = fmaf(h0.y, wv[1][d], p);
        p = fmaf(h0.z, wv[2][d], p); p = fmaf(h0.w, wv[3][d], p);
        p = fmaf(h1.x, wv[4][d], p); p = fmaf(h1.y, wv[5][d], p);
        p = fmaf(h1.z, wv[6][d], p); p = fmaf(h1.w, wv[7][d], p);
    }
    p += __shfl_xor(p, 1);              // combine c-halves
    const float anew = p * (1.0f / 256.0f);
    float bv = anew;
    if (!FIRST) bv += bij[gi * OC + oo];
    float mx = bv;                       // softmax over o: lanes differ in bits 1..3
    mx = fmaxf(mx, __shfl_xor(mx, 2));
    mx = fmaxf(mx, __shfl_xor(mx, 4));
    mx = fmaxf(mx, __shfl_xor(mx, 8));
    const float e = expf(bv - mx);
    float ssum = e;
    ssum += __shfl_xor(ssum, 2);
    ssum += __shfl_xor(ssum, 4);
    ssum += __shfl_xor(ssum, 8);
    if (ch == 0 && (i0 + il) < IC) {
        bij[gi * OC + oo] = bv;
        cij[gi * OC + oo] = e / ssum;
    }
}

extern "C" void kernel_launch(void* const* d_in, const int* in_sizes, int n_in,
                              void* d_out, int out_size, void* d_ws, size_t ws_size,
                              hipStream_t stream)
{
    const float* x = (const float*)d_in[0];   // [256, 2401, 8]
    const float* W = (const float*)d_in[1];   // [2401, 8, 16, 8]
    float* out = (float*)d_out;               // [256, 8, 16]

    int ni = 128;                             // split-K chunks for s_kernel
    while (ni > 1 &&
           (size_t)ni * BSZ * OCC * 4 + (size_t)BSZ * OCC * 4 + (size_t)IC * OC * 8 > ws_size)
        ni >>= 1;
    const int chunk = (IC + ni - 1) / ni;

    float* spart = (float*)d_ws;                       // [ni][256][128]
    float* v     = spart + (size_t)ni * BSZ * OCC;     // [256][128]
    float* bij   = v + (size_t)BSZ * OCC;              // [2401][8]
    float* cij   = bij + (size_t)IC * OC;              // [2401][8]

    const dim3 sgrid(4, ni);
    const int ablocks = (IC + 7) / 8;   // 301

    s_kernel<true><<<sgrid, 128, 0, stream>>>(x, W, nullptr, spart, chunk);
    squash_kernel<<<32, 256, 0, stream>>>(spart, v, ni);
    a_kernel<true><<<ablocks, 128, 0, stream>>>(x, W, v, bij, cij);

    s_kernel<false><<<sgrid, 128, 0, stream>>>(x, W, cij, spart, chunk);
    squash_kernel<<<32, 256, 0, stream>>>(spart, v, ni);
    a_kernel<false><<<ablocks, 128, 0, stream>>>(x, W, v, bij, cij);

    s_kernel<false><<<sgrid, 128, 0, stream>>>(x, W, cij, spart, chunk);
    squash_kernel<<<32, 256, 0, stream>>>(spart, out, ni);
}

// Round 3
// 235.695 us; speedup vs baseline: 14.6616x; 1.6159x over previous
//
#include <hip/hip_runtime.h>
#include <math.h>

#define IC   2401
#define BSZ  256
#define D    8
#define OC   8
#define CS   16
#define OCC  128   // OC*CS
#define KTOT 301   // ceil(2401/8) K-tiles of 64 (8 i's)

typedef __attribute__((ext_vector_type(8))) short short8;
typedef __attribute__((ext_vector_type(4))) float f32x4;

__device__ __forceinline__ unsigned short f2bf(float f) {
    union { float f; unsigned u; } v; v.f = f;
    const unsigned r = v.u + 0x7FFF + ((v.u >> 16) & 1);   // RNE
    return (unsigned short)(r >> 16);
}

// -------- s partials via bf16 MFMA: spart[iy][b][oc] += x[b,k] * (c o W)[k,oc]
// K = i*8+d (19208). grid (4 b-groups, ni k-slices), 256 thr = 4 waves.
// Block output 64b x 128oc; wave: 16b x 128oc = 8 accumulators of 16x16.
// Staging converts fp32->bf16 and folds c into W (also zeroes i>=IC tails).
template<bool FIRST>
__global__ __launch_bounds__(256, 2)
void s_gemm(const float* __restrict__ x, const float* __restrict__ W,
            const float* __restrict__ cij, float* __restrict__ spart)
{
    __shared__ __align__(16) unsigned short Xs[64 * 72];    // [b][k] pad 72
    __shared__ __align__(16) unsigned short Bs[128 * 72];   // [oc][k] pad 72

    const int tid = threadIdx.x;
    const int bg  = blockIdx.x;        // 0..3
    const int iy  = blockIdx.y;        // 0..ni-1
    const int nk  = gridDim.y;
    const int b0  = bg * 64;
    const int ln  = tid & 63;
    const int m0  = (tid >> 6) * 16;   // wave's 16 b-rows
    const int mr  = ln & 15;
    const int qd  = ln >> 4;           // quad 0..3

    f32x4 acc[8];
#pragma unroll
    for (int n = 0; n < 8; ++n) acc[n] = (f32x4){0.f, 0.f, 0.f, 0.f};

    for (int kt = iy; kt < KTOT; kt += nk) {
        __syncthreads();
        // ---- stage Xs: x[b0..b0+63][kt*64 .. +63] fp32 -> bf16
#pragma unroll
        for (int q = 0; q < 2; ++q) {
            const int g   = q * 256 + tid;       // 0..511
            const int row = g >> 3, gk = g & 7;  // 8-float granules
            int gran = kt * 8 + gk;              // global granule (x row = 2401 granules)
            if (gran > 2400) gran = 2400;        // tail clamp (zeroed by Bs)
            const float4* xp = (const float4*)(x + (size_t)(b0 + row) * 19208 + (size_t)gran * 8);
            const float4 u0 = xp[0], u1 = xp[1];
            union { short8 v; unsigned short h[8]; } o;
            o.h[0] = f2bf(u0.x); o.h[1] = f2bf(u0.y); o.h[2] = f2bf(u0.z); o.h[3] = f2bf(u0.w);
            o.h[4] = f2bf(u1.x); o.h[5] = f2bf(u1.y); o.h[6] = f2bf(u1.z); o.h[7] = f2bf(u1.w);
            *(short8*)&Xs[row * 72 + gk * 8] = o.v;
        }
        // ---- stage Bs: (c o W)^T tile, [oc][il*8+d], c=cij[i][oc>>4]
#pragma unroll
        for (int q = 0; q < 4; ++q) {
            const int it = q * 256 + tid;        // 0..1023
            const int il = it >> 7, oc = it & 127;
            const int i  = kt * 8 + il;
            float c = 0.0f;
            if (i < IC) c = FIRST ? 0.125f : cij[i * OC + (oc >> 4)];
            const int ic = (i < IC) ? i : (IC - 1);
            const float4* wp = (const float4*)(W + ((size_t)ic * 128 + oc) * 8);
            const float4 u0 = wp[0], u1 = wp[1];
            union { short8 v; unsigned short h[8]; } o;
            o.h[0] = f2bf(c * u0.x); o.h[1] = f2bf(c * u0.y);
            o.h[2] = f2bf(c * u0.z); o.h[3] = f2bf(c * u0.w);
            o.h[4] = f2bf(c * u1.x); o.h[5] = f2bf(c * u1.y);
            o.h[6] = f2bf(c * u1.z); o.h[7] = f2bf(c * u1.w);
            *(short8*)&Bs[oc * 72 + il * 8] = o.v;
        }
        __syncthreads();
        // ---- MFMA: 2 k-halves x 8 n-tiles
#pragma unroll
        for (int kk = 0; kk < 2; ++kk) {
            const int kof = kk * 32 + qd * 8;
            const short8 a = *(const short8*)&Xs[(m0 + mr) * 72 + kof];
#pragma unroll
            for (int n = 0; n < 8; ++n) {
                const short8 b = *(const short8*)&Bs[(n * 16 + mr) * 72 + kof];
                acc[n] = __builtin_amdgcn_mfma_f32_16x16x32_bf16(a, b, acc[n], 0, 0, 0);
            }
        }
    }

    // write-out: C/D layout col=lane&15, row=quad*4+reg
    float* op = spart + ((size_t)iy * BSZ + b0) * OCC;
#pragma unroll
    for (int n = 0; n < 8; ++n) {
        const int col = n * 16 + mr;
#pragma unroll
        for (int r = 0; r < 4; ++r)
            op[(size_t)(m0 + qd * 4 + r) * OCC + col] = acc[n][r];
    }
}

// -------- reduce ni split-K partials + squash. 32 blocks x 256 thr; 64 rows/block,
// 4 k-quarters per row (one per wave), LDS reduce.
__global__ __launch_bounds__(256)
void squash_kernel(const float* __restrict__ spart, float* __restrict__ vout, int ni)
{
    __shared__ float red[256 * 17];
    const int tid = threadIdx.x;
    const int r   = tid & 63;
    const int kq  = tid >> 6;
    const int row = blockIdx.x * 64 + r;   // (b,o) row 0..2047

    float s[CS];
#pragma unroll
    for (int j = 0; j < CS; ++j) s[j] = 0.0f;

    for (int k = kq; k < ni; k += 4) {
        const float4* p = (const float4*)(spart + (size_t)k * BSZ * OCC + (size_t)row * CS);
#pragma unroll
        for (int q = 0; q < 4; ++q) {
            const float4 t = p[q];
            s[4 * q + 0] += t.x; s[4 * q + 1] += t.y;
            s[4 * q + 2] += t.z; s[4 * q + 3] += t.w;
        }
    }
#pragma unroll
    for (int j = 0; j < CS; ++j) red[tid * 17 + j] = s[j];
    __syncthreads();
    if (tid < 64) {
#pragma unroll
        for (int j = 0; j < CS; ++j)
            s[j] = red[r * 17 + j] + red[(64 + r) * 17 + j]
                 + red[(128 + r) * 17 + j] + red[(192 + r) * 17 + j];
        float ms = 0.0f;
#pragma unroll
        for (int j = 0; j < CS; ++j) ms = fmaf(s[j], s[j], ms);
        const float scale = sqrtf(ms) / (1.0f + ms);   // == mag_sq/(1+mag_sq)/mag
        float4* o4 = (float4*)(vout + (size_t)row * CS);
#pragma unroll
        for (int q = 0; q < 4; ++q)
            o4[q] = make_float4(s[4 * q + 0] * scale, s[4 * q + 1] * scale,
                                s[4 * q + 2] * scale, s[4 * q + 3] * scale);
    }
}

// -------- agreement: block = 8 i's. Phase 1: H[(i,d)][oc] = sum_b x[b,i,d]*v[b,oc]
// (64x128x256 GEMM, x/v in LDS, 8x8 reg tile). Phase 2: a[i,o] = sum_{c,d} W*H,
// fused b_ij update + softmax. No spills, no cross-block reduction.
template<bool FIRST>
__global__ __launch_bounds__(128, 2)
void a_kernel(const float* __restrict__ x, const float* __restrict__ W,
              const float* __restrict__ v, float* __restrict__ bij,
              float* __restrict__ cij)
{
    __shared__ float sm[4352 + 8960];   // 53.25 KB
    float* xls = sm;                    // [64 b][68]  rows i*8+d
    float* vls = sm + 4352;             // [64 b][140] swizzle oc + (oc>>5)*4

    const int tid = threadIdx.x;        // 0..127
    const int i0  = blockIdx.x * 8;
    const int rg  = tid >> 4;           // 0..7 -> rows r0..r0+7 (one i)
    const int cg  = tid & 15;           // cols c0..c0+7
    const int r0  = rg * 8;
    const int c0  = cg * 8;
    const int cp  = c0 + ((c0 >> 5) << 2);

    float acc[8][8];
#pragma unroll
    for (int a = 0; a < 8; ++a)
#pragma unroll
        for (int b = 0; b < 8; ++b) acc[a][b] = 0.0f;

    const float4* x4 = (const float4*)x;
    const float4* v4 = (const float4*)v;

    for (int bc = 0; bc < 4; ++bc) {    // batch chunks of 64
        const int b0 = bc * 64;
        __syncthreads();
        {
            const int b = tid >> 1, j = tid & 1;
            const size_t xb = (size_t)(b0 + b) * IC;
#pragma unroll
            for (int k = 0; k < 8; ++k) {
                const int f  = j * 8 + k;
                const int il = f >> 1, h = f & 1;
                const int gi = min(i0 + il, IC - 1);
                *(float4*)&xls[b * 68 + il * 8 + h * 4] = x4[(xb + gi) * 2 + h];
            }
            const size_t vb = (size_t)(b0 + b) * 32;
#pragma unroll
            for (int k = 0; k < 16; ++k) {
                const int q  = j * 16 + k;      // float4 slot 0..31
                const int oc = q * 4;
                *(float4*)&vls[b * 140 + oc + ((oc >> 5) << 2)] = v4[vb + q];
            }
        }
        __syncthreads();
#pragma unroll 2
        for (int bb = 0; bb < 64; ++bb) {
            const float4 x0 = *(const float4*)&xls[bb * 68 + r0];
            const float4 x1 = *(const float4*)&xls[bb * 68 + r0 + 4];
            const float4 va = *(const float4*)&vls[bb * 140 + cp];
            const float4 vb2 = *(const float4*)&vls[bb * 140 + cp + 4];
            const float xr[8] = {x0.x, x0.y, x0.z, x0.w, x1.x, x1.y, x1.z, x1.w};
            const float vr[8] = {va.x, va.y, va.z, va.w, vb2.x, vb2.y, vb2.z, vb2.w};
#pragma unroll
            for (int rr = 0; rr < 8; ++rr)
#pragma unroll
                for (int cc = 0; cc < 8; ++cc)
                    acc[rr][cc] = fmaf(xr[rr], vr[cc], acc[rr][cc]);
        }
    }

    __syncthreads();
    float* H = sm;                      // [64 rows][132]
#pragma unroll
    for (int rr = 0; rr < 8; ++rr) {
        *(float4*)&H[(r0 + rr) * 132 + c0]     = make_float4(acc[rr][0], acc[rr][1], acc[rr][2], acc[rr][3]);
        *(float4*)&H[(r0 + rr) * 132 + c0 + 4] = make_float4(acc[rr][4], acc[rr][5], acc[rr][6], acc[rr][7]);
    }
    __syncthreads();

    // phase 2: tid = il*16 + oo*2 + ch ; each (il,oo) split over 2 c-halves
    const int il = tid >> 4;
    const int oo = (tid >> 1) & 7;
    const int ch = tid & 1;
    const int gi = min(i0 + il, IC - 1);
    const float4* Wg = (const float4*)W + ((size_t)gi * 128 + oo * 16 + ch * 8) * 2;

    float wv[8][8];
#pragma unroll
    for (int cc = 0; cc < 8; ++cc) {
        const float4 a0 = Wg[cc * 2], a1 = Wg[cc * 2 + 1];
        wv[cc][0] = a0.x; wv[cc][1] = a0.y; wv[cc][2] = a0.z; wv[cc][3] = a0.w;
        wv[cc][4] = a1.x; wv[cc][5] = a1.y; wv[cc][6] = a1.z; wv[cc][7] = a1.w;
    }
    float p = 0.0f;
#pragma unroll
    for (int d = 0; d < 8; ++d) {
        const float* hr = &H[(il * 8 + d) * 132 + oo * 16 + ch * 8];
        const float4 h0 = *(const float4*)hr;
        const float4 h1 = *(const float4*)(hr + 4);
        p = fmaf(h0.x, wv[0][d], p); p = fmaf(h0.y, wv[1][d], p);
        p = fmaf(h0.z, wv[2][d], p); p = fmaf(h0.w, wv[3][d], p);
        p = fmaf(h1.x, wv[4][d], p); p = fmaf(h1.y, wv[5][d], p);
        p = fmaf(h1.z, wv[6][d], p); p = fmaf(h1.w, wv[7][d], p);
    }
    p += __shfl_xor(p, 1);              // combine c-halves
    const float anew = p * (1.0f / 256.0f);
    float bv = anew;
    if (!FIRST) bv += bij[gi * OC + oo];
    float mx = bv;                       // softmax over o: lanes differ in bits 1..3
    mx = fmaxf(mx, __shfl_xor(mx, 2));
    mx = fmaxf(mx, __shfl_xor(mx, 4));
    mx = fmaxf(mx, __shfl_xor(mx, 8));
    const float e = expf(bv - mx);
    float ssum = e;
    ssum += __shfl_xor(ssum, 2);
    ssum += __shfl_xor(ssum, 4);
    ssum += __shfl_xor(ssum, 8);
    if (ch == 0 && (i0 + il) < IC) {
        bij[gi * OC + oo] = bv;
        cij[gi * OC + oo] = e / ssum;
    }
}

extern "C" void kernel_launch(void* const* d_in, const int* in_sizes, int n_in,
                              void* d_out, int out_size, void* d_ws, size_t ws_size,
                              hipStream_t stream)
{
    const float* x = (const float*)d_in[0];   // [256, 2401, 8]
    const float* W = (const float*)d_in[1];   // [2401, 8, 16, 8]
    float* out = (float*)d_out;               // [256, 8, 16]

    int ni = 128;                             // split-K slices for s_gemm
    while (ni > 1 &&
           (size_t)ni * BSZ * OCC * 4 + (size_t)BSZ * OCC * 4 + (size_t)IC * OC * 8 > ws_size)
        ni >>= 1;

    float* spart = (float*)d_ws;                       // [ni][256][128]
    float* v     = spart + (size_t)ni * BSZ * OCC;     // [256][128]
    float* bij   = v + (size_t)BSZ * OCC;              // [2401][8]
    float* cij   = bij + (size_t)IC * OC;              // [2401][8]

    const dim3 sgrid(4, ni);
    const int ablocks = (IC + 7) / 8;   // 301

    s_gemm<true><<<sgrid, 256, 0, stream>>>(x, W, nullptr, spart);
    squash_kernel<<<32, 256, 0, stream>>>(spart, v, ni);
    a_kernel<true><<<ablocks, 128, 0, stream>>>(x, W, v, bij, cij);

    s_gemm<false><<<sgrid, 256, 0, stream>>>(x, W, cij, spart);
    squash_kernel<<<32, 256, 0, stream>>>(spart, v, ni);
    a_kernel<false><<<ablocks, 128, 0, stream>>>(x, W, v, bij, cij);

    s_gemm<false><<<sgrid, 256, 0, stream>>>(x, W, cij, spart);
    squash_kernel<<<32, 256, 0, stream>>>(spart, out, ni);
}

// Round 4
// 162.022 us; speedup vs baseline: 21.3283x; 1.4547x over previous
//
#include <hip/hip_runtime.h>
#include <math.h>

#define IC    2401
#define BSZ   256
#define OC    8
#define CS    16
#define OCC   128     // OC*CS
#define XROW  19208   // x row length (floats) = IC*8
#define KP    19264   // padded K (=301*64), pad region is zeroed
#define KTILES 301

typedef __attribute__((ext_vector_type(8))) short short8;
typedef __attribute__((ext_vector_type(4))) float f32x4;

__device__ __forceinline__ unsigned short f2bf(float f) {
    union { float f; unsigned u; } v; v.f = f;
    const unsigned r = v.u + 0x7FFF + ((v.u >> 16) & 1);   // RNE
    return (unsigned short)(r >> 16);
}

// ---------------- cvt: xT[k][b] bf16, k = i*8+d (padded to KP with zeros) ------------
__global__ __launch_bounds__(256)
void cvt_kernel(const float* __restrict__ x, unsigned short* __restrict__ xT)
{
    __shared__ float Ts[64 * 65];
    const int tid = threadIdx.x;
    const int bg  = blockIdx.x;      // 0..3
    const int kt  = blockIdx.y;      // 0..300
    // load tile x[bg*64+b][kt*64 + c] (fp32, coalesced); OOB cols -> 0
#pragma unroll
    for (int r = 0; r < 4; ++r) {
        const int flat = r * 256 + tid;          // 1024 float4s
        const int b = flat >> 4, cq = flat & 15;
        const int col = kt * 64 + cq * 4;
        float4 v = make_float4(0.f, 0.f, 0.f, 0.f);
        if (col < XROW) v = *(const float4*)(x + (size_t)(bg * 64 + b) * XROW + col);
        *(float4*)&Ts[b * 65 + cq * 4] = v;
    }
    __syncthreads();
    // store transposed: xT[kt*64+rl][bg*64 + bq*8 .. +8]
#pragma unroll
    for (int r = 0; r < 2; ++r) {
        const int flat = r * 256 + tid;          // 512 granules
        const int rl = flat >> 3, bq = flat & 7;
        union { short8 v; unsigned short h[8]; } o;
#pragma unroll
        for (int j = 0; j < 8; ++j) o.h[j] = f2bf(Ts[(bq * 8 + j) * 65 + rl]);
        *(short8*)(xT + (size_t)(kt * 64 + rl) * 256 + bg * 64 + bq * 8) = o.v;
    }
}

// ---------------- prep0: cw_t[oc][i*8+d] = 0.125*W[i][oc][d], zero pad i>2400 --------
__global__ __launch_bounds__(256)
void prep0_kernel(const float* __restrict__ W, unsigned short* __restrict__ cwt)
{
    __shared__ float Ws[8 * 1032];
    const int tid = threadIdx.x;
    const int i0  = blockIdx.x * 8;
#pragma unroll
    for (int r = 0; r < 8; ++r) {
        const int flat = r * 256 + tid;          // 2048 float4s
        const int g = flat >> 8, rem = flat & 255;
        int gi = i0 + g; if (gi > 2400) gi = 2400;
        const float4 v = *(const float4*)(W + (size_t)gi * 1024 + rem * 4);
        *(float4*)&Ws[g * 1032 + rem * 4] = v;
    }
    __syncthreads();
#pragma unroll
    for (int r = 0; r < 4; ++r) {
        const int flat = r * 256 + tid;          // 1024 granules
        const int oc = flat >> 3, g = flat & 7;
        const int gi = i0 + g;
        union { short8 v; unsigned short h[8]; } o;
        if (gi <= 2400) {
            const float* wp = &Ws[g * 1032 + oc * 8];
#pragma unroll
            for (int j = 0; j < 8; ++j) o.h[j] = f2bf(0.125f * wp[j]);
        } else {
#pragma unroll
            for (int j = 0; j < 8; ++j) o.h[j] = 0;
        }
        *(short8*)(cwt + (size_t)oc * KP + (size_t)gi * 8) = o.v;
    }
}

// ---------------- s partials: spart[iy][b][oc] = sum_k x[b,k]*cw_t[oc,k] -------------
// grid (4 bg, ni), 256 thr = 4 waves; block 64b x 128oc; XOR-swizzled LDS granules.
__global__ __launch_bounds__(256, 4)
void s_gemm(const float* __restrict__ x, const unsigned short* __restrict__ cwt,
            float* __restrict__ spart)
{
    __shared__ __align__(16) unsigned short Xs[64 * 64];    // 8 KB
    __shared__ __align__(16) unsigned short Bs[128 * 64];   // 16 KB
    const int tid = threadIdx.x;
    const int bg  = blockIdx.x, iy = blockIdx.y, ni = gridDim.y;
    const int b0  = bg * 64;
    const int ln  = tid & 63;
    const int m0  = (tid >> 6) * 16;
    const int mr  = ln & 15, qd = ln >> 4;

    f32x4 acc[8];
#pragma unroll
    for (int n = 0; n < 8; ++n) acc[n] = (f32x4){0.f, 0.f, 0.f, 0.f};

    for (int kt = iy; kt < KTILES; kt += ni) {
        __syncthreads();
        // Xs: convert x fp32->bf16 (k-tail reads clamped; killed by zero Bs rows)
#pragma unroll
        for (int r = 0; r < 2; ++r) {
            const int flat = r * 256 + tid;
            const int b = flat >> 3, col = flat & 7;
            int gq = kt * 8 + col; if (gq > 2400) gq = 2400;
            const float4* xp = (const float4*)(x + (size_t)(b0 + b) * XROW + (size_t)gq * 8);
            const float4 u0 = xp[0], u1 = xp[1];
            union { short8 v; unsigned short h[8]; } o;
            o.h[0] = f2bf(u0.x); o.h[1] = f2bf(u0.y); o.h[2] = f2bf(u0.z); o.h[3] = f2bf(u0.w);
            o.h[4] = f2bf(u1.x); o.h[5] = f2bf(u1.y); o.h[6] = f2bf(u1.z); o.h[7] = f2bf(u1.w);
            *(short8*)&Xs[b * 64 + ((col ^ (b & 7)) * 8)] = o.v;
        }
        // Bs: plain bf16 copy of cw_t rows
#pragma unroll
        for (int r = 0; r < 4; ++r) {
            const int flat = r * 256 + tid;
            const int oc = flat >> 3, col = flat & 7;
            const short8 w = *(const short8*)(cwt + (size_t)oc * KP + (size_t)(kt * 8 + col) * 8);
            *(short8*)&Bs[oc * 64 + ((col ^ (oc & 7)) * 8)] = w;
        }
        __syncthreads();
#pragma unroll
        for (int kk = 0; kk < 2; ++kk) {
            const int csw = ((kk * 4 + qd) ^ (mr & 7)) * 8;
            const short8 a = *(const short8*)&Xs[(m0 + mr) * 64 + csw];
#pragma unroll
            for (int nt = 0; nt < 8; ++nt) {
                const short8 b = *(const short8*)&Bs[(nt * 16 + mr) * 64 + csw];
                acc[nt] = __builtin_amdgcn_mfma_f32_16x16x32_bf16(a, b, acc[nt], 0, 0, 0);
            }
        }
    }

    float* op = spart + ((size_t)iy * BSZ + b0) * OCC;
#pragma unroll
    for (int nt = 0; nt < 8; ++nt)
#pragma unroll
        for (int r = 0; r < 4; ++r)
            op[(size_t)(m0 + qd * 4 + r) * OCC + nt * 16 + mr] = acc[nt][r];
}

// ---------------- reduce split-K + squash; writes vT bf16 (iters) or vout fp32 (final)
__global__ __launch_bounds__(256)
void squash_kernel(const float* __restrict__ spart, float* __restrict__ vout,
                   unsigned short* __restrict__ vT, int ni, int writeT)
{
    __shared__ float red[256 * 17];
    const int tid = threadIdx.x;
    const int r   = tid & 63;
    const int kq  = tid >> 6;
    const int row = blockIdx.x * 64 + r;   // (b,o) row 0..2047

    float s[CS];
#pragma unroll
    for (int j = 0; j < CS; ++j) s[j] = 0.0f;
    for (int k = kq; k < ni; k += 4) {
        const float4* p = (const float4*)(spart + (size_t)k * BSZ * OCC + (size_t)row * CS);
#pragma unroll
        for (int q = 0; q < 4; ++q) {
            const float4 t = p[q];
            s[4 * q + 0] += t.x; s[4 * q + 1] += t.y;
            s[4 * q + 2] += t.z; s[4 * q + 3] += t.w;
        }
    }
#pragma unroll
    for (int j = 0; j < CS; ++j) red[tid * 17 + j] = s[j];
    __syncthreads();
    if (tid < 64) {
#pragma unroll
        for (int j = 0; j < CS; ++j)
            s[j] = red[r * 17 + j] + red[(64 + r) * 17 + j]
                 + red[(128 + r) * 17 + j] + red[(192 + r) * 17 + j];
        float ms = 0.0f;
#pragma unroll
        for (int j = 0; j < CS; ++j) ms = fmaf(s[j], s[j], ms);
        const float scale = sqrtf(ms) / (1.0f + ms);
        if (writeT) {
            const int b = row >> 3, o = row & 7;
#pragma unroll
            for (int j = 0; j < CS; ++j)
                vT[(size_t)(o * 16 + j) * 256 + b] = f2bf(s[j] * scale);
        } else {
            float4* o4 = (float4*)(vout + (size_t)row * CS);
#pragma unroll
            for (int q = 0; q < 4; ++q)
                o4[q] = make_float4(s[4 * q + 0] * scale, s[4 * q + 1] * scale,
                                    s[4 * q + 2] * scale, s[4 * q + 3] * scale);
        }
    }
}

// ---------------- agreement (MFMA) + bij update + softmax + write cw_t for next iter
// Block = 8 i's. Phase 1: H[oc][(i,d)] = sum_b vT[oc][b]*xT[(i,d)][b] (M=128,N=64,K=256).
// Phase 2: a[i,o] = (1/256) sum_{c,d} W[i,o,c,d]*H[o*16+c][i*8+d]; fused softmax;
// epilogue writes cw_t[oc][k] = c[i,o]*W[i,o,c,d] (zeros for pad i).
template<bool FIRST>
__global__ __launch_bounds__(256, 2)
void a_gemm(const unsigned short* __restrict__ xT, const unsigned short* __restrict__ vT,
            const float* __restrict__ W, float* __restrict__ bij,
            unsigned short* __restrict__ cwt)
{
    __shared__ __align__(16) char smraw[128 * 68 * 4];      // 34816 B (staging 24576 aliased)
    unsigned short* As = (unsigned short*)smraw;            // [128 oc][64 b]
    unsigned short* Bx = (unsigned short*)(smraw + 16384);  // [64 (i,d)][64 b]
    float* Hs = (float*)smraw;                              // [128][68]

    const int tid = threadIdx.x;
    const int i0  = blockIdx.x * 8;
    const int ln  = tid & 63, wv = tid >> 6;
    const int mr  = ln & 15, qd = ln >> 4;

    f32x4 acc[2][4];
#pragma unroll
    for (int a = 0; a < 2; ++a)
#pragma unroll
        for (int b = 0; b < 4; ++b) acc[a][b] = (f32x4){0.f, 0.f, 0.f, 0.f};

    for (int bc = 0; bc < 4; ++bc) {
        __syncthreads();
#pragma unroll
        for (int r = 0; r < 4; ++r) {          // As <- vT tile
            const int flat = r * 256 + tid;
            const int oc = flat >> 3, col = flat & 7;
            const short8 v = *(const short8*)(vT + (size_t)oc * 256 + bc * 64 + col * 8);
            *(short8*)&As[oc * 64 + ((col ^ (oc & 7)) * 8)] = v;
        }
#pragma unroll
        for (int r = 0; r < 2; ++r) {          // Bx <- xT rows i0*8..i0*8+63
            const int flat = r * 256 + tid;
            const int rw = flat >> 3, col = flat & 7;
            const short8 v = *(const short8*)(xT + (size_t)(i0 * 8 + rw) * 256 + bc * 64 + col * 8);
            *(short8*)&Bx[rw * 64 + ((col ^ (rw & 7)) * 8)] = v;
        }
        __syncthreads();
#pragma unroll
        for (int kk = 0; kk < 2; ++kk) {
            const int csw = ((kk * 4 + qd) ^ (mr & 7)) * 8;
#pragma unroll
            for (int nt = 0; nt < 4; ++nt) {
                const short8 b = *(const short8*)&Bx[(nt * 16 + mr) * 64 + csw];
#pragma unroll
                for (int mt = 0; mt < 2; ++mt) {
                    const short8 a = *(const short8*)&As[((wv * 2 + mt) * 16 + mr) * 64 + csw];
                    acc[mt][nt] = __builtin_amdgcn_mfma_f32_16x16x32_bf16(a, b, acc[mt][nt], 0, 0, 0);
                }
            }
        }
    }

    __syncthreads();
#pragma unroll
    for (int mt = 0; mt < 2; ++mt)
#pragma unroll
        for (int nt = 0; nt < 4; ++nt)
#pragma unroll
            for (int r = 0; r < 4; ++r)
                Hs[((wv * 2 + mt) * 16 + qd * 4 + r) * 68 + nt * 16 + mr] = acc[mt][nt][r];
    __syncthreads();

    // phase 2: tid = il*32 + oo*4 + ch
    const int ch = tid & 3, oo = (tid >> 2) & 7, il = tid >> 5;
    const int ival = i0 + il;
    const int gi = (ival < IC) ? ival : IC - 1;
    const float* Wt = W + (size_t)gi * 1024 + oo * 128 + ch * 32;

    float wreg[4][8];
#pragma unroll
    for (int c = 0; c < 4; ++c) {
        const float4 w0 = *(const float4*)(Wt + c * 8);
        const float4 w1 = *(const float4*)(Wt + c * 8 + 4);
        wreg[c][0] = w0.x; wreg[c][1] = w0.y; wreg[c][2] = w0.z; wreg[c][3] = w0.w;
        wreg[c][4] = w1.x; wreg[c][5] = w1.y; wreg[c][6] = w1.z; wreg[c][7] = w1.w;
    }
    float p = 0.0f;
#pragma unroll
    for (int c = 0; c < 4; ++c) {
        const float* hr = &Hs[(oo * 16 + ch * 4 + c) * 68 + il * 8];
        const float4 h0 = *(const float4*)hr;
        const float4 h1 = *(const float4*)(hr + 4);
        p = fmaf(wreg[c][0], h0.x, p); p = fmaf(wreg[c][1], h0.y, p);
        p = fmaf(wreg[c][2], h0.z, p); p = fmaf(wreg[c][3], h0.w, p);
        p = fmaf(wreg[c][4], h1.x, p); p = fmaf(wreg[c][5], h1.y, p);
        p = fmaf(wreg[c][6], h1.z, p); p = fmaf(wreg[c][7], h1.w, p);
    }
    p += __shfl_xor(p, 1); p += __shfl_xor(p, 2);   // combine ch quarters
    const float anew = p * (1.0f / 256.0f);
    float bv = anew;
    if (!FIRST) bv += bij[gi * 8 + oo];
    float mx = bv;                                   // softmax over oo (bits 2..4)
    mx = fmaxf(mx, __shfl_xor(mx, 4));
    mx = fmaxf(mx, __shfl_xor(mx, 8));
    mx = fmaxf(mx, __shfl_xor(mx, 16));
    const float e = expf(bv - mx);
    float ss = e;
    ss += __shfl_xor(ss, 4); ss += __shfl_xor(ss, 8); ss += __shfl_xor(ss, 16);
    float cv = e / ss;
    if (ival >= IC) cv = 0.0f;                      // zero the pad rows of cw_t
    if (ch == 0 && ival < IC) bij[ival * 8 + oo] = bv;
#pragma unroll
    for (int c = 0; c < 4; ++c) {
        union { short8 v; unsigned short h[8]; } o;
#pragma unroll
        for (int j = 0; j < 8; ++j) o.h[j] = f2bf(cv * wreg[c][j]);
        *(short8*)(cwt + (size_t)(oo * 16 + ch * 4 + c) * KP + (size_t)ival * 8) = o.v;
    }
}

extern "C" void kernel_launch(void* const* d_in, const int* in_sizes, int n_in,
                              void* d_out, int out_size, void* d_ws, size_t ws_size,
                              hipStream_t stream)
{
    const float* x = (const float*)d_in[0];   // [256, 2401, 8]
    const float* W = (const float*)d_in[1];   // [2401, 8, 16, 8]
    float* out = (float*)d_out;               // [256, 8, 16]

    const size_t xT_b  = (size_t)KP * 256 * 2;      // 9,863,168
    const size_t cwt_b = (size_t)128 * KP * 2;      // 4,931,584
    const size_t vT_b  = 128 * 256 * 2;             // 65,536
    const size_t bij_b = IC * 8 * 4;                // 76,832
    const size_t fixed = xT_b + cwt_b + vT_b + bij_b;

    int ni = 128;
    while (ni > 4 && (size_t)ni * BSZ * OCC * 4 + fixed > ws_size) ni >>= 1;

    char* p = (char*)d_ws;
    float*          spart = (float*)p;          p += (size_t)ni * BSZ * OCC * 4;
    unsigned short* xT    = (unsigned short*)p; p += xT_b;
    unsigned short* cwt   = (unsigned short*)p; p += cwt_b;
    unsigned short* vT    = (unsigned short*)p; p += vT_b;
    float*          bij   = (float*)p;

    const dim3 sgrid(4, ni);

    cvt_kernel<<<dim3(4, KTILES), 256, 0, stream>>>(x, xT);
    prep0_kernel<<<KTILES, 256, 0, stream>>>(W, cwt);

    // iter 0
    s_gemm<<<sgrid, 256, 0, stream>>>(x, cwt, spart);
    squash_kernel<<<32, 256, 0, stream>>>(spart, nullptr, vT, ni, 1);
    a_gemm<true><<<KTILES, 256, 0, stream>>>(xT, vT, W, bij, cwt);
    // iter 1
    s_gemm<<<sgrid, 256, 0, stream>>>(x, cwt, spart);
    squash_kernel<<<32, 256, 0, stream>>>(spart, nullptr, vT, ni, 1);
    a_gemm<false><<<KTILES, 256, 0, stream>>>(xT, vT, W, bij, cwt);
    // iter 2 (final)
    s_gemm<<<sgrid, 256, 0, stream>>>(x, cwt, spart);
    squash_kernel<<<32, 256, 0, stream>>>(spart, out, vT, ni, 0);
}

// Round 5
// 144.021 us; speedup vs baseline: 23.9942x; 1.1250x over previous
//
#include <hip/hip_runtime.h>
#include <math.h>

#define IC     2401
#define BSZ    256
#define OC     8
#define CS     16
#define OCC    128     // OC*CS
#define XROW   19208   // x row length (floats) = IC*8
#define KP     19264   // padded K (=301*64 = 2408 granules of 8), pad zeroed
#define KTILES 301
#define NI     64      // split-K slices for s_gemm

typedef __attribute__((ext_vector_type(8))) short short8;
typedef __attribute__((ext_vector_type(4))) float f32x4;

__device__ __forceinline__ unsigned short f2bf(float f) {
    union { float f; unsigned u; } v; v.f = f;
    const unsigned r = v.u + 0x7FFF + ((v.u >> 16) & 1);   // RNE
    return (unsigned short)(r >> 16);
}
__device__ __forceinline__ float bf2f(unsigned short h) {
    union { unsigned u; float f; } v; v.u = ((unsigned)h) << 16;
    return v.f;
}

// ---------------- prep (one launch): blocks 0..1203 -> xT + xB ; 1204..1504 -> Wbf + cwt0
__global__ __launch_bounds__(256)
void prep_kernel(const float* __restrict__ x, const float* __restrict__ W,
                 unsigned short* __restrict__ xT, unsigned short* __restrict__ xB,
                 unsigned short* __restrict__ Wbf, unsigned short* __restrict__ cwt)
{
    const int tid = threadIdx.x;
    if (blockIdx.x < 1204) {
        __shared__ float Ts[64 * 65];
        const int bg = blockIdx.x & 3;       // b-group of 64
        const int kt = blockIdx.x >> 2;      // k-tile 0..300
#pragma unroll
        for (int r = 0; r < 4; ++r) {
            const int flat = r * 256 + tid;  // 1024 float4s
            const int b = flat >> 4, cq = flat & 15;
            const int col = kt * 64 + cq * 4;
            float4 v = make_float4(0.f, 0.f, 0.f, 0.f);
            if (col < XROW) v = *(const float4*)(x + (size_t)(bg * 64 + b) * XROW + col);
            *(float4*)&Ts[b * 65 + cq * 4] = v;
        }
        __syncthreads();
        // xT[k][b] (transposed)
#pragma unroll
        for (int r = 0; r < 2; ++r) {
            const int flat = r * 256 + tid;  // 512 granules
            const int rl = flat >> 3, bq = flat & 7;
            union { short8 v; unsigned short h[8]; } o;
#pragma unroll
            for (int j = 0; j < 8; ++j) o.h[j] = f2bf(Ts[(bq * 8 + j) * 65 + rl]);
            *(short8*)(xT + (size_t)(kt * 64 + rl) * 256 + bg * 64 + bq * 8) = o.v;
        }
        // xB[b][k] (row-major bf16, padded)
#pragma unroll
        for (int r = 0; r < 2; ++r) {
            const int flat = r * 256 + tid;  // 512 granules
            const int b = flat >> 3, g = flat & 7;
            union { short8 v; unsigned short h[8]; } o;
#pragma unroll
            for (int j = 0; j < 8; ++j) o.h[j] = f2bf(Ts[b * 65 + g * 8 + j]);
            *(short8*)(xB + (size_t)(bg * 64 + b) * KP + (size_t)kt * 64 + g * 8) = o.v;
        }
    } else {
        __shared__ float Ws[8 * 1032];
        const int i0 = (blockIdx.x - 1204) * 8;
#pragma unroll
        for (int r = 0; r < 8; ++r) {
            const int flat = r * 256 + tid;  // 2048 float4s
            const int g = flat >> 8, rem = flat & 255;
            int gi = i0 + g; if (gi > 2400) gi = 2400;
            const float4 v = *(const float4*)(W + (size_t)gi * 1024 + rem * 4);
            *(float4*)&Ws[g * 1032 + rem * 4] = v;
        }
        __syncthreads();
#pragma unroll
        for (int r = 0; r < 4; ++r) {
            const int flat = r * 256 + tid;  // 1024 granules
            const int oc = flat >> 3, g = flat & 7;
            const int gi = i0 + g;
            union { short8 v; unsigned short h[8]; } w, c;
            if (gi <= 2400) {
                const float* wp = &Ws[g * 1032 + oc * 8];
#pragma unroll
                for (int j = 0; j < 8; ++j) {
                    w.h[j] = f2bf(wp[j]);
                    c.h[j] = f2bf(0.125f * wp[j]);
                }
            } else {
#pragma unroll
                for (int j = 0; j < 8; ++j) { w.h[j] = 0; c.h[j] = 0; }
            }
            *(short8*)(Wbf + (size_t)oc * KP + (size_t)gi * 8) = w.v;
            *(short8*)(cwt + (size_t)oc * KP + (size_t)gi * 8) = c.v;
        }
    }
}

// ---------------- s partials: spart[iy][b][oc] = sum_k xB[b,k]*cwt[oc,k]
// grid (4 bg, NI), 256 thr = 4 waves. Block 64b x 128oc; wave 32b x 64oc (2m x 4n).
__global__ __launch_bounds__(256, 2)
void s_gemm(const unsigned short* __restrict__ xB, const unsigned short* __restrict__ cwt,
            float* __restrict__ spart)
{
    __shared__ __align__(16) unsigned short Xs[64 * 64];    // 8 KB
    __shared__ __align__(16) unsigned short Bs[128 * 64];   // 16 KB
    const int tid = threadIdx.x;
    const int bg  = blockIdx.x, iy = blockIdx.y;
    const int b0  = bg * 64;
    const int ln  = tid & 63;
    const int mr  = ln & 15, qd = ln >> 4;
    const int mh  = (tid >> 6) & 1;        // m-half (32 b-rows)
    const int nh  = tid >> 7;              // n-half (64 oc)

    f32x4 acc[2][4];
#pragma unroll
    for (int a = 0; a < 2; ++a)
#pragma unroll
        for (int b = 0; b < 4; ++b) acc[a][b] = (f32x4){0.f, 0.f, 0.f, 0.f};

    for (int kt = iy; kt < KTILES; kt += NI) {
        __syncthreads();
#pragma unroll
        for (int r = 0; r < 2; ++r) {        // Xs <- xB (pure bf16 copy)
            const int flat = r * 256 + tid;
            const int b = flat >> 3, col = flat & 7;
            const short8 v = *(const short8*)(xB + (size_t)(b0 + b) * KP + (size_t)(kt * 8 + col) * 8);
            *(short8*)&Xs[b * 64 + ((col ^ (b & 7)) * 8)] = v;
        }
#pragma unroll
        for (int r = 0; r < 4; ++r) {        // Bs <- cwt
            const int flat = r * 256 + tid;
            const int oc = flat >> 3, col = flat & 7;
            const short8 w = *(const short8*)(cwt + (size_t)oc * KP + (size_t)(kt * 8 + col) * 8);
            *(short8*)&Bs[oc * 64 + ((col ^ (oc & 7)) * 8)] = w;
        }
        __syncthreads();
#pragma unroll
        for (int kk = 0; kk < 2; ++kk) {
            const int csw = ((kk * 4 + qd) ^ (mr & 7)) * 8;
            const short8 a0 = *(const short8*)&Xs[(mh * 32 + mr) * 64 + csw];
            const short8 a1 = *(const short8*)&Xs[(mh * 32 + 16 + mr) * 64 + csw];
#pragma unroll
            for (int nt = 0; nt < 4; ++nt) {
                const short8 b = *(const short8*)&Bs[(nh * 64 + nt * 16 + mr) * 64 + csw];
                acc[0][nt] = __builtin_amdgcn_mfma_f32_16x16x32_bf16(a0, b, acc[0][nt], 0, 0, 0);
                acc[1][nt] = __builtin_amdgcn_mfma_f32_16x16x32_bf16(a1, b, acc[1][nt], 0, 0, 0);
            }
        }
    }

    float* op = spart + ((size_t)iy * BSZ + b0) * OCC;
#pragma unroll
    for (int mt = 0; mt < 2; ++mt)
#pragma unroll
        for (int nt = 0; nt < 4; ++nt)
#pragma unroll
            for (int r = 0; r < 4; ++r)
                op[(size_t)(mh * 32 + mt * 16 + qd * 4 + r) * OCC + nh * 64 + nt * 16 + mr]
                    = acc[mt][nt][r];
}

// ---------------- reduce NI split-K partials + squash, full-chip spread.
// grid 256 blocks x 256 thr; block = 8 (b,o)-rows; 2-way k split per element.
__global__ __launch_bounds__(256)
void squash_kernel(const float* __restrict__ spart, float* __restrict__ vout,
                   unsigned short* __restrict__ vT, int writeT)
{
    __shared__ float red[256];
    const int tid = threadIdx.x;
    const int r0  = blockIdx.x * 8;          // first of 8 rows (row = b*8+o)
    const int idx = tid & 127;               // element within 8x16 chunk
    const int k0  = tid >> 7;                // k parity

    const float* base = spart + (size_t)r0 * 16 + idx;
    float acc = 0.0f;
#pragma unroll 8
    for (int k = k0; k < NI; k += 2) acc += base[(size_t)k * (BSZ * OCC)];
    red[tid] = acc;
    __syncthreads();

    if (tid < 128) {
        const float s = red[tid] + red[tid + 128];
        float ms = s * s;
        ms += __shfl_xor(ms, 1); ms += __shfl_xor(ms, 2);
        ms += __shfl_xor(ms, 4); ms += __shfl_xor(ms, 8);
        const float scale = sqrtf(ms) / (1.0f + ms);   // == mag_sq/(1+mag_sq)/mag
        const float outv = s * scale;
        const int row = r0 + (tid >> 4);     // = b*8 + o
        const int j   = tid & 15;
        if (writeT) {
            vT[(size_t)((row & 7) * 16 + j) * 256 + (row >> 3)] = f2bf(outv);
        } else {
            vout[(size_t)row * 16 + j] = outv;
        }
    }
}

// ---------------- agreement (MFMA) + bij + softmax + write cwt for next iter.
// Block = 8 i's. Phase 1: H[oc][(i,d)] = sum_b vT[oc][b]*xT[(i,d)][b].
// Phase 2: a[i,o] = (1/256) sum_{c,d} Wbf*H; softmax over o; cwt = c*Wbf.
template<bool FIRST>
__global__ __launch_bounds__(256, 2)
void a_gemm(const unsigned short* __restrict__ xT, const unsigned short* __restrict__ vT,
            const unsigned short* __restrict__ Wbf, float* __restrict__ bij,
            unsigned short* __restrict__ cwt)
{
    __shared__ __align__(16) char smraw[128 * 68 * 4];      // 34816 B (staging aliased)
    unsigned short* As = (unsigned short*)smraw;            // [128 oc][64 b]
    unsigned short* Bx = (unsigned short*)(smraw + 16384);  // [64 (i,d)][64 b]
    float* Hs = (float*)smraw;                              // [128][68]

    const int tid = threadIdx.x;
    const int i0  = blockIdx.x * 8;
    const int ln  = tid & 63, wv = tid >> 6;
    const int mr  = ln & 15, qd = ln >> 4;

    f32x4 acc[2][4];
#pragma unroll
    for (int a = 0; a < 2; ++a)
#pragma unroll
        for (int b = 0; b < 4; ++b) acc[a][b] = (f32x4){0.f, 0.f, 0.f, 0.f};

    for (int bc = 0; bc < 4; ++bc) {
        __syncthreads();
#pragma unroll
        for (int r = 0; r < 4; ++r) {          // As <- vT tile
            const int flat = r * 256 + tid;
            const int oc = flat >> 3, col = flat & 7;
            const short8 v = *(const short8*)(vT + (size_t)oc * 256 + bc * 64 + col * 8);
            *(short8*)&As[oc * 64 + ((col ^ (oc & 7)) * 8)] = v;
        }
#pragma unroll
        for (int r = 0; r < 2; ++r) {          // Bx <- xT rows i0*8..+63
            const int flat = r * 256 + tid;
            const int rw = flat >> 3, col = flat & 7;
            const short8 v = *(const short8*)(xT + (size_t)(i0 * 8 + rw) * 256 + bc * 64 + col * 8);
            *(short8*)&Bx[rw * 64 + ((col ^ (rw & 7)) * 8)] = v;
        }
        __syncthreads();
#pragma unroll
        for (int kk = 0; kk < 2; ++kk) {
            const int csw = ((kk * 4 + qd) ^ (mr & 7)) * 8;
#pragma unroll
            for (int nt = 0; nt < 4; ++nt) {
                const short8 b = *(const short8*)&Bx[(nt * 16 + mr) * 64 + csw];
#pragma unroll
                for (int mt = 0; mt < 2; ++mt) {
                    const short8 a = *(const short8*)&As[((wv * 2 + mt) * 16 + mr) * 64 + csw];
                    acc[mt][nt] = __builtin_amdgcn_mfma_f32_16x16x32_bf16(a, b, acc[mt][nt], 0, 0, 0);
                }
            }
        }
    }

    __syncthreads();
#pragma unroll
    for (int mt = 0; mt < 2; ++mt)
#pragma unroll
        for (int nt = 0; nt < 4; ++nt)
#pragma unroll
            for (int r = 0; r < 4; ++r)
                Hs[((wv * 2 + mt) * 16 + qd * 4 + r) * 68 + nt * 16 + mr] = acc[mt][nt][r];
    __syncthreads();

    // phase 2: tid = il*32 + oo*4 + ch
    const int ch = tid & 3, oo = (tid >> 2) & 7, il = tid >> 5;
    const int ival = i0 + il;
    const int gi = (ival < IC) ? ival : IC - 1;
    const unsigned short* Wt = Wbf + (size_t)(oo * 16 + ch * 4) * KP + (size_t)gi * 8;

    float wreg[4][8];
#pragma unroll
    for (int c = 0; c < 4; ++c) {
        union { short8 v; unsigned short h[8]; } uw;
        uw.v = *(const short8*)(Wt + (size_t)c * KP);
#pragma unroll
        for (int j = 0; j < 8; ++j) wreg[c][j] = bf2f(uw.h[j]);
    }
    float p = 0.0f;
#pragma unroll
    for (int c = 0; c < 4; ++c) {
        const float* hr = &Hs[(oo * 16 + ch * 4 + c) * 68 + il * 8];
        const float4 h0 = *(const float4*)hr;
        const float4 h1 = *(const float4*)(hr + 4);
        p = fmaf(wreg[c][0], h0.x, p); p = fmaf(wreg[c][1], h0.y, p);
        p = fmaf(wreg[c][2], h0.z, p); p = fmaf(wreg[c][3], h0.w, p);
        p = fmaf(wreg[c][4], h1.x, p); p = fmaf(wreg[c][5], h1.y, p);
        p = fmaf(wreg[c][6], h1.z, p); p = fmaf(wreg[c][7], h1.w, p);
    }
    p += __shfl_xor(p, 1); p += __shfl_xor(p, 2);   // combine ch quarters
    const float anew = p * (1.0f / 256.0f);
    float bv = anew;
    if (!FIRST) bv += bij[gi * 8 + oo];
    float mx = bv;                                   // softmax over oo (bits 2..4)
    mx = fmaxf(mx, __shfl_xor(mx, 4));
    mx = fmaxf(mx, __shfl_xor(mx, 8));
    mx = fmaxf(mx, __shfl_xor(mx, 16));
    const float e = expf(bv - mx);
    float ss = e;
    ss += __shfl_xor(ss, 4); ss += __shfl_xor(ss, 8); ss += __shfl_xor(ss, 16);
    float cv = e / ss;
    if (ival >= IC) cv = 0.0f;                       // keep cwt pad rows zero
    if (ch == 0 && ival < IC) bij[ival * 8 + oo] = bv;
#pragma unroll
    for (int c = 0; c < 4; ++c) {
        union { short8 v; unsigned short h[8]; } o;
#pragma unroll
        for (int j = 0; j < 8; ++j) o.h[j] = f2bf(cv * wreg[c][j]);
        *(short8*)(cwt + (size_t)(oo * 16 + ch * 4 + c) * KP + (size_t)ival * 8) = o.v;
    }
}

extern "C" void kernel_launch(void* const* d_in, const int* in_sizes, int n_in,
                              void* d_out, int out_size, void* d_ws, size_t ws_size,
                              hipStream_t stream)
{
    const float* x = (const float*)d_in[0];   // [256, 2401, 8]
    const float* W = (const float*)d_in[1];   // [2401, 8, 16, 8]
    float* out = (float*)d_out;               // [256, 8, 16]

    char* p = (char*)d_ws;
    float*          spart = (float*)p;          p += (size_t)NI * BSZ * OCC * 4;   // 8.39 MB
    unsigned short* xT    = (unsigned short*)p; p += (size_t)KP * 256 * 2;         // 9.86 MB
    unsigned short* xB    = (unsigned short*)p; p += (size_t)256 * KP * 2;         // 9.86 MB
    unsigned short* Wbf   = (unsigned short*)p; p += (size_t)128 * KP * 2;         // 4.93 MB
    unsigned short* cwt   = (unsigned short*)p; p += (size_t)128 * KP * 2;         // 4.93 MB
    unsigned short* vT    = (unsigned short*)p; p += (size_t)128 * 256 * 2;        // 64 KB
    float*          bij   = (float*)p;                                            // 77 KB

    const dim3 sgrid(4, NI);

    prep_kernel<<<1505, 256, 0, stream>>>(x, W, xT, xB, Wbf, cwt);

    // iter 0
    s_gemm<<<sgrid, 256, 0, stream>>>(xB, cwt, spart);
    squash_kernel<<<256, 256, 0, stream>>>(spart, nullptr, vT, 1);
    a_gemm<true><<<KTILES, 256, 0, stream>>>(xT, vT, Wbf, bij, cwt);
    // iter 1
    s_gemm<<<sgrid, 256, 0, stream>>>(xB, cwt, spart);
    squash_kernel<<<256, 256, 0, stream>>>(spart, nullptr, vT, 1);
    a_gemm<false><<<KTILES, 256, 0, stream>>>(xT, vT, Wbf, bij, cwt);
    // iter 2 (final)
    s_gemm<<<sgrid, 256, 0, stream>>>(xB, cwt, spart);
    squash_kernel<<<256, 256, 0, stream>>>(spart, out, vT, 0);
}